// Round 6
// baseline (36.622 us; speedup 1.0000x reference)
//
#include <hip/hip_runtime.h>

// s[n,k] = x[n]·coords[k] + ||coords[k]||^2 ; out[n,k] = (second_min_j s[n,j]) > s[n,k]
// Block: 64 rows x 128 cols, 512 threads. Thread tile 8x16, K-split S=8 (quad-interleaved:
// split s owns dim-quads Q with Q%8==s). coords resident in LDS as cst[d][c ^ (Q&7)*4]
// (XOR swizzle -> B-reads spread evenly across bank quads). Split-partials reduced with
// a register butterfly (shfl_xor 1/2/4). Norms hoisted to prologue.

__global__ __launch_bounds__(512, 2)
void kmad_main(const float* __restrict__ x, const float* __restrict__ coords,
               int* __restrict__ out) {
    __shared__ float lds[32768 + 4096 + 128];   // 144.5 KB
    float* const cst   = lds;                   // [256][128] swizzled
    float* const xs    = lds + 32768;           // [64][64] chunk
    float* const norms = lds + 32768 + 4096;    // [128]

    const int t    = threadIdx.x;
    const int lane = t & 63;
    const int sp   = lane & 7;          // split: owns quads Q%8==sp
    const int cg   = (lane >> 3) & 7;   // colgroup: cols cg*16..+16
    const int rg   = t >> 6;            // rowgroup = wave: rows rg*8..+8
    const int r0   = rg * 8;
    const int c0   = cg * 16;
    const int row0 = blockIdx.x * 64;
    const int swz  = sp * 4;

    // ---- stage cst[d][c ^ (Q&7)*4] = coords[c][d] via in-register 4x4 transpose ----
    {
        const int cq = t & 31;          // column quad
        const int qb = t >> 5;          // 0..15
        #pragma unroll
        for (int k = 0; k < 4; ++k) {
            const int Q = qb + 16 * k;
            const float4 v0 = *(const float4*)&coords[(size_t)(cq * 4 + 0) * 256 + Q * 4];
            const float4 v1 = *(const float4*)&coords[(size_t)(cq * 4 + 1) * 256 + Q * 4];
            const float4 v2 = *(const float4*)&coords[(size_t)(cq * 4 + 2) * 256 + Q * 4];
            const float4 v3 = *(const float4*)&coords[(size_t)(cq * 4 + 3) * 256 + Q * 4];
            const int csw = (cq * 4) ^ ((Q & 7) * 4);
            *(float4*)&cst[(size_t)(Q * 4 + 0) * 128 + csw] = make_float4(v0.x, v1.x, v2.x, v3.x);
            *(float4*)&cst[(size_t)(Q * 4 + 1) * 128 + csw] = make_float4(v0.y, v1.y, v2.y, v3.y);
            *(float4*)&cst[(size_t)(Q * 4 + 2) * 128 + csw] = make_float4(v0.z, v1.z, v2.z, v3.z);
            *(float4*)&cst[(size_t)(Q * 4 + 3) * 128 + csw] = make_float4(v0.w, v1.w, v2.w, v3.w);
        }
    }

    // ---- norms[c] = ||coords[c]||^2 (prologue, L2-hot) ----
    {
        const int c = t >> 2, part = t & 3;
        const float4* cp = (const float4*)(coords + (size_t)c * 256 + part * 64);
        float na = 0.f;
        #pragma unroll
        for (int q = 0; q < 16; ++q) {
            float4 v = cp[q];
            na = fmaf(v.x, v.x, na); na = fmaf(v.y, v.y, na);
            na = fmaf(v.z, v.z, na); na = fmaf(v.w, v.w, na);
        }
        na += __shfl_xor(na, 1);
        na += __shfl_xor(na, 2);
        if (part == 0) norms[c] = na;
    }

    // ---- prefetch x chunk 0 (thread stages row t>>3, quads (t&7), (t&7)+8) ----
    const int srow = t >> 3, q0 = t & 7;
    const float* xr = x + (size_t)(row0 + srow) * 256;
    float4 pf0 = *(const float4*)&xr[(q0) * 4];
    float4 pf1 = *(const float4*)&xr[(q0 + 8) * 4];

    float acc[8][16] = {};

    #pragma unroll 1
    for (int ch = 0; ch < 4; ++ch) {
        *(float4*)&xs[srow * 64 + q0 * 4]       = pf0;
        *(float4*)&xs[srow * 64 + (q0 + 8) * 4] = pf1;
        __syncthreads();   // (ch 0: also covers cst+norms staging)

        if (ch < 3) {
            pf0 = *(const float4*)&xr[((ch + 1) * 16 + q0) * 4];
            pf1 = *(const float4*)&xr[((ch + 1) * 16 + q0 + 8) * 4];
        }

        #pragma unroll
        for (int p = 0; p < 2; ++p) {
            const int Qloc = sp + 8 * p;
            float4 ar[8];
            #pragma unroll
            for (int i = 0; i < 8; ++i)
                ar[i] = *(const float4*)&xs[(r0 + i) * 64 + Qloc * 4];
            const int dbase = (ch * 16 + Qloc) * 4;
            #pragma unroll
            for (int j = 0; j < 4; ++j) {
                const float* crow = cst + (size_t)(dbase + j) * 128;
                float4 b[4];
                #pragma unroll
                for (int u = 0; u < 4; ++u)
                    b[u] = *(const float4*)&crow[(c0 + u * 4) ^ swz];
                #pragma unroll
                for (int i = 0; i < 8; ++i) {
                    const float a = (j == 0) ? ar[i].x : (j == 1) ? ar[i].y
                                  : (j == 2) ? ar[i].z : ar[i].w;
                    #pragma unroll
                    for (int u = 0; u < 4; ++u) {
                        acc[i][u * 4 + 0] = fmaf(a, b[u].x, acc[i][u * 4 + 0]);
                        acc[i][u * 4 + 1] = fmaf(a, b[u].y, acc[i][u * 4 + 1]);
                        acc[i][u * 4 + 2] = fmaf(a, b[u].z, acc[i][u * 4 + 2]);
                        acc[i][u * 4 + 3] = fmaf(a, b[u].w, acc[i][u * 4 + 3]);
                    }
                }
            }
        }
        __syncthreads();   // xs safe to overwrite
    }

    // ---- butterfly-sum split partials (lanes xor 1,2,4) -> all split-lanes identical ----
    #pragma unroll
    for (int i = 0; i < 8; ++i) {
        #pragma unroll
        for (int k = 0; k < 16; ++k) {
            float v = acc[i][k];
            v += __shfl_xor(v, 1);
            v += __shfl_xor(v, 2);
            v += __shfl_xor(v, 4);
            acc[i][k] = v;
        }
    }

    float nv[16];
    #pragma unroll
    for (int u = 0; u < 4; ++u) {
        float4 n4 = *(const float4*)&norms[c0 + u * 4];
        nv[u * 4 + 0] = n4.x; nv[u * 4 + 1] = n4.y;
        nv[u * 4 + 2] = n4.z; nv[u * 4 + 3] = n4.w;
    }

    // ---- per-row second-min over 128 cols (dense for all 8 rows) ----
    float m2f[8];
    #pragma unroll
    for (int i = 0; i < 8; ++i) {
        float m1, m2;
        {
            const float s0 = acc[i][0] + nv[0];
            const float s1 = acc[i][1] + nv[1];
            m1 = fminf(s0, s1);
            m2 = fmaxf(s0, s1);
        }
        #pragma unroll
        for (int k = 2; k < 16; ++k) {
            const float sk = acc[i][k] + nv[k];
            const float hi = fmaxf(m1, sk);
            m1 = fminf(m1, sk);
            m2 = fminf(m2, hi);
        }
        #pragma unroll
        for (int m = 8; m <= 32; m <<= 1) {   // merge across cg lanes
            const float o1 = __shfl_xor(m1, m);
            const float o2 = __shfl_xor(m2, m);
            m2 = fminf(fmaxf(m1, o1), fminf(m2, o2));
            m1 = fminf(m1, o1);
        }
        m2f[i] = m2;
    }

    // ---- masked stores: split-lane sp stores row r0+sp (static indexing only) ----
    #pragma unroll
    for (int i = 0; i < 8; ++i) {
        if (sp == i) {
            int* op = out + (size_t)(row0 + r0 + i) * 128 + c0;
            #pragma unroll
            for (int u = 0; u < 4; ++u) {
                int4 o;
                o.x = (m2f[i] > acc[i][u * 4 + 0] + nv[u * 4 + 0]) ? 1 : 0;
                o.y = (m2f[i] > acc[i][u * 4 + 1] + nv[u * 4 + 1]) ? 1 : 0;
                o.z = (m2f[i] > acc[i][u * 4 + 2] + nv[u * 4 + 2]) ? 1 : 0;
                o.w = (m2f[i] > acc[i][u * 4 + 3] + nv[u * 4 + 3]) ? 1 : 0;
                *(int4*)(op + u * 4) = o;
            }
        }
    }
}

extern "C" void kernel_launch(void* const* d_in, const int* in_sizes, int n_in,
                              void* d_out, int out_size, void* d_ws, size_t ws_size,
                              hipStream_t stream) {
    const float* x      = (const float*)d_in[0];   // (16384, 256) fp32
    const float* coords = (const float*)d_in[1];   // (128, 256)   fp32
    int* out = (int*)d_out;                        // (16384, 128) bool -> int32 0/1
    kmad_main<<<256, 512, 0, stream>>>(x, coords, out);
}